// Round 1
// baseline (26.256 us; speedup 1.0000x reference)
//
#include <hip/hip_runtime.h>

#define EPS 1e-7f

// Kernel A: sig = sigmoid(lut), [N*64] floats, vectorized float4.
__global__ void sigmoid_kernel(const float* __restrict__ lut,
                               float* __restrict__ sig, int n4) {
    int i = blockIdx.x * blockDim.x + threadIdx.x;
    if (i < n4) {
        float4 v = reinterpret_cast<const float4*>(lut)[i];
        float4 o;
        o.x = 1.0f / (1.0f + __expf(-v.x));
        o.y = 1.0f / (1.0f + __expf(-v.y));
        o.z = 1.0f / (1.0f + __expf(-v.z));
        o.w = 1.0f / (1.0f + __expf(-v.w));
        reinterpret_cast<float4*>(sig)[i] = o;
    }
}

// Main kernel: each thread owns one n (holds w[64] = sigmoid(lut[n,:]) in
// registers) and iterates over b. Block = 64 n × 4 parallel b; wave lanes
// cover 64 consecutive n -> fully contiguous input reads / output writes.
// grid.x = N/64, grid.y = B/32 (8 b-iterations per thread).
template <bool INLINE_SIG>
__global__ __launch_bounds__(256) void lut_kernel(const float* __restrict__ in,
                                                  const float* __restrict__ wsrc,
                                                  float* __restrict__ out,
                                                  int N) {
    const int n  = blockIdx.x * 64 + (threadIdx.x & 63);
    const int b0 = blockIdx.y * 32 + (threadIdx.x >> 6);

    float w[64];
    const float4* wp = reinterpret_cast<const float4*>(wsrc + (size_t)n * 64);
    #pragma unroll
    for (int k = 0; k < 16; ++k) {
        float4 v = wp[k];
        if (INLINE_SIG) {
            w[4*k+0] = 1.0f / (1.0f + __expf(-v.x));
            w[4*k+1] = 1.0f / (1.0f + __expf(-v.y));
            w[4*k+2] = 1.0f / (1.0f + __expf(-v.z));
            w[4*k+3] = 1.0f / (1.0f + __expf(-v.w));
        } else {
            w[4*k+0] = v.x; w[4*k+1] = v.y; w[4*k+2] = v.z; w[4*k+3] = v.w;
        }
    }

    #pragma unroll 2
    for (int it = 0; it < 8; ++it) {
        const int b = b0 + it * 4;
        const float2* ip =
            reinterpret_cast<const float2*>(in + ((size_t)b * N + n) * 6);
        float2 v0 = ip[0], v1 = ip[1], v2 = ip[2];
        float x[6] = {v0.x, v0.y, v1.x, v1.y, v2.x, v2.y};

        // A[j] = relu(x_j)+eps (table bit 0), Bv[j] = relu(1-x_j)+eps (bit 1)
        float A[6], Bv[6];
        #pragma unroll
        for (int j = 0; j < 6; ++j) {
            A[j]  = fmaxf(x[j], 0.0f) + EPS;
            Bv[j] = fmaxf(1.0f - x[j], 0.0f) + EPS;
        }

        // i = b0*32+b1*16+b2*8 + b3*4+b4*2+b5  (MSB-first bits of table idx)
        float t01[4];
        t01[0] = A[0]*A[1];  t01[1] = A[0]*Bv[1];
        t01[2] = Bv[0]*A[1]; t01[3] = Bv[0]*Bv[1];
        float t34[4];
        t34[0] = A[3]*A[4];  t34[1] = A[3]*Bv[4];
        t34[2] = Bv[3]*A[4]; t34[3] = Bv[3]*Bv[4];

        float thi[8], tlo[8];
        #pragma unroll
        for (int h = 0; h < 8; ++h) {
            thi[h] = t01[h >> 1] * ((h & 1) ? Bv[2] : A[2]);
            tlo[h] = t34[h >> 1] * ((h & 1) ? Bv[5] : A[5]);
        }

        float acc = 0.0f;
        #pragma unroll
        for (int h = 0; h < 8; ++h) {
            float s = 0.0f;
            #pragma unroll
            for (int l = 0; l < 8; ++l) s = fmaf(tlo[l], w[h * 8 + l], s);
            acc = fmaf(thi[h], s, acc);
        }
        out[(size_t)b * N + n] = acc;
    }
}

extern "C" void kernel_launch(void* const* d_in, const int* in_sizes, int n_in,
                              void* d_out, int out_size, void* d_ws, size_t ws_size,
                              hipStream_t stream) {
    const float* inputs = (const float*)d_in[0];   // [B, N, 6] f32
    const float* lut    = (const float*)d_in[1];   // [N, 64]  f32
    float* out = (float*)d_out;                    // [B, N]   f32

    const int lut_sz = in_sizes[1];                // N*64
    const int N = lut_sz / 64;
    const int B = in_sizes[0] / (6 * N);

    dim3 grid(N / 64, B / 32);

    if (ws_size >= (size_t)lut_sz * sizeof(float)) {
        float* sig = (float*)d_ws;
        const int n4 = lut_sz / 4;
        sigmoid_kernel<<<(n4 + 255) / 256, 256, 0, stream>>>(lut, sig, n4);
        lut_kernel<false><<<grid, 256, 0, stream>>>(inputs, sig, out, N);
    } else {
        lut_kernel<true><<<grid, 256, 0, stream>>>(inputs, lut, out, N);
    }
}

// Round 2
// 25.740 us; speedup vs baseline: 1.0200x; 1.0200x over previous
//
#include <hip/hip_runtime.h>

#define EPS 1e-7f

// Kernel A: sig = sigmoid(lut), [N*64] floats, vectorized float4.
__global__ void sigmoid_kernel(const float* __restrict__ lut,
                               float* __restrict__ sig, int n4) {
    int i = blockIdx.x * blockDim.x + threadIdx.x;
    if (i < n4) {
        float4 v = reinterpret_cast<const float4*>(lut)[i];
        float4 o;
        o.x = 1.0f / (1.0f + __expf(-v.x));
        o.y = 1.0f / (1.0f + __expf(-v.y));
        o.z = 1.0f / (1.0f + __expf(-v.z));
        o.w = 1.0f / (1.0f + __expf(-v.w));
        reinterpret_cast<float4*>(sig)[i] = o;
    }
}

// Main kernel: thread owns one n (w[64] in registers), iterates 8 b values.
// Block = 64 n × 4 parallel b; wave lanes cover 64 consecutive n ->
// contiguous input reads / output writes. grid = (N/64, B/32).
// __launch_bounds__(256,4): cap VGPR at 128 so 4 blocks/CU are resident
// (grid is exactly 4 blocks/CU -> one full round, no idle tail).
template <bool INLINE_SIG>
__global__ __launch_bounds__(256, 4) void lut_kernel(const float* __restrict__ in,
                                                     const float* __restrict__ wsrc,
                                                     float* __restrict__ out,
                                                     int N) {
    const int n  = blockIdx.x * 64 + (threadIdx.x & 63);
    const int b0 = blockIdx.y * 32 + (threadIdx.x >> 6);

    float w[64];
    const float4* wp = reinterpret_cast<const float4*>(wsrc + (size_t)n * 64);
    #pragma unroll
    for (int k = 0; k < 16; ++k) {
        float4 v = wp[k];
        if (INLINE_SIG) {
            w[4*k+0] = 1.0f / (1.0f + __expf(-v.x));
            w[4*k+1] = 1.0f / (1.0f + __expf(-v.y));
            w[4*k+2] = 1.0f / (1.0f + __expf(-v.z));
            w[4*k+3] = 1.0f / (1.0f + __expf(-v.w));
        } else {
            w[4*k+0] = v.x; w[4*k+1] = v.y; w[4*k+2] = v.z; w[4*k+3] = v.w;
        }
    }

    const size_t base = (size_t)b0 * N + n;
    const float2* ip = reinterpret_cast<const float2*>(in + base * 6);
    float* op = out + base;
    const size_t bstride2 = (size_t)4 * N * 3;  // 4 b-rows, in float2 units

    // rotating-register prefetch of the 24 B input for the next iteration
    float2 p0 = ip[0], p1 = ip[1], p2 = ip[2];

    #pragma unroll 2
    for (int it = 0; it < 8; ++it) {
        const float2 v0 = p0, v1 = p1, v2 = p2;
        if (it < 7) {
            const float2* np = ip + (size_t)(it + 1) * bstride2;
            p0 = np[0]; p1 = np[1]; p2 = np[2];
        }
        const float x0 = v0.x, x1 = v0.y, x2 = v1.x,
                    x3 = v1.y, x4 = v2.x, x5 = v2.y;

        // A = relu(x)+eps (bit==1 in table), Bv = relu(1-x)+eps (bit==0)
        const float A0 = fmaxf(x0, 0.0f) + EPS, B0 = fmaxf(1.0f - x0, 0.0f) + EPS;
        const float A1 = fmaxf(x1, 0.0f) + EPS, B1 = fmaxf(1.0f - x1, 0.0f) + EPS;
        const float A2 = fmaxf(x2, 0.0f) + EPS, B2 = fmaxf(1.0f - x2, 0.0f) + EPS;
        const float A3 = fmaxf(x3, 0.0f) + EPS, B3 = fmaxf(1.0f - x3, 0.0f) + EPS;
        const float A4 = fmaxf(x4, 0.0f) + EPS, B4 = fmaxf(1.0f - x4, 0.0f) + EPS;
        const float A5 = fmaxf(x5, 0.0f) + EPS, B5 = fmaxf(1.0f - x5, 0.0f) + EPS;

        // table idx i = b0*32+b1*16+b2*8 + b3*4+b4*2+b5 (MSB-first)
        float t01[4];
        t01[0] = A0 * A1;  t01[1] = A0 * B1;
        t01[2] = B0 * A1;  t01[3] = B0 * B1;
        float t34[4];
        t34[0] = A3 * A4;  t34[1] = A3 * B4;
        t34[2] = B3 * A4;  t34[3] = B3 * B4;

        float tlo[8];
        #pragma unroll
        for (int h = 0; h < 8; ++h)
            tlo[h] = t34[h >> 1] * ((h & 1) ? B5 : A5);

        float acc = 0.0f;
        #pragma unroll
        for (int h = 0; h < 8; ++h) {
            float s = 0.0f;
            #pragma unroll
            for (int l = 0; l < 8; ++l) s = fmaf(tlo[l], w[h * 8 + l], s);
            const float thi = t01[h >> 1] * ((h & 1) ? B2 : A2);  // on the fly
            acc = fmaf(thi, s, acc);
        }
        op[(size_t)it * 4 * N] = acc;
    }
}

extern "C" void kernel_launch(void* const* d_in, const int* in_sizes, int n_in,
                              void* d_out, int out_size, void* d_ws, size_t ws_size,
                              hipStream_t stream) {
    const float* inputs = (const float*)d_in[0];   // [B, N, 6] f32
    const float* lut    = (const float*)d_in[1];   // [N, 64]  f32
    float* out = (float*)d_out;                    // [B, N]   f32

    const int lut_sz = in_sizes[1];                // N*64
    const int N = lut_sz / 64;
    const int B = in_sizes[0] / (6 * N);

    dim3 grid(N / 64, B / 32);

    if (ws_size >= (size_t)lut_sz * sizeof(float)) {
        float* sig = (float*)d_ws;
        const int n4 = lut_sz / 4;
        sigmoid_kernel<<<(n4 + 255) / 256, 256, 0, stream>>>(lut, sig, n4);
        lut_kernel<false><<<grid, 256, 0, stream>>>(inputs, sig, out, N);
    } else {
        lut_kernel<true><<<grid, 256, 0, stream>>>(inputs, lut, out, N);
    }
}

// Round 3
// 17.222 us; speedup vs baseline: 1.5246x; 1.4946x over previous
//
#include <hip/hip_runtime.h>

#define EPS 1e-7f

// One kernel. Each block owns 64 consecutive n. The 64x64 sigmoid(lut) tile
// is staged via LDS with COALESCED global loads (the previous version did a
// 64-line-per-instruction register gather -> ~268 MB of L2 transactions for a
// 512 KB table). Each thread then holds its n-row w[64] in registers and
// iterates 8 b values. Block = 64 n x 4 parallel b. grid = (N/64, B/32)
// = 1024 blocks = 4/CU, all resident (launch_bounds caps VGPR at 128).
__global__ __launch_bounds__(256, 4) void lut_kernel(const float* __restrict__ in,
                                                     const float* __restrict__ lut,
                                                     float* __restrict__ out,
                                                     int N) {
    __shared__ float wsm[64][65];  // +1 pad: bank = (n+k) mod 32 -> conflict-free

    const int t  = threadIdx.x;
    const int n0 = blockIdx.x * 64;
    const int n  = n0 + (t & 63);
    const int b0 = blockIdx.y * 32 + (t >> 6);

    // --- stage sigmoid(lut[n0..n0+63][0..63]) into LDS, coalesced ---
    {
        const float4* lp = reinterpret_cast<const float4*>(lut + (size_t)n0 * 64);
        const int r  = t >> 2;        // row 0..63
        const int c4 = t & 3;         // float4 slot 0..3
        #pragma unroll
        for (int p = 0; p < 4; ++p) {
            const int s = c4 + p * 4;             // float4 slot 0..15
            float4 v = lp[r * 16 + s];            // wave: 4 KB contiguous
            wsm[r][s * 4 + 0] = 1.0f / (1.0f + __expf(-v.x));
            wsm[r][s * 4 + 1] = 1.0f / (1.0f + __expf(-v.y));
            wsm[r][s * 4 + 2] = 1.0f / (1.0f + __expf(-v.z));
            wsm[r][s * 4 + 3] = 1.0f / (1.0f + __expf(-v.w));
        }
    }
    __syncthreads();

    // --- copy this thread's w row into registers (conflict-free b128 reads) ---
    float w[64];
    {
        const int nl = t & 63;
        #pragma unroll
        for (int k = 0; k < 16; ++k) {
            float4 v = *reinterpret_cast<const float4*>(&wsm[nl][k * 4]);
            w[4*k+0] = v.x; w[4*k+1] = v.y; w[4*k+2] = v.z; w[4*k+3] = v.w;
        }
    }

    const size_t base = (size_t)b0 * N + n;
    const float2* ip = reinterpret_cast<const float2*>(in + base * 6);
    float* op = out + base;
    const size_t bstride2 = (size_t)4 * N * 3;  // 4 b-rows, in float2 units

    // rotating-register prefetch of the 24 B input for the next iteration
    float2 p0 = ip[0], p1 = ip[1], p2 = ip[2];

    #pragma unroll 2
    for (int it = 0; it < 8; ++it) {
        const float2 v0 = p0, v1 = p1, v2 = p2;
        if (it < 7) {
            const float2* np = ip + (size_t)(it + 1) * bstride2;
            p0 = np[0]; p1 = np[1]; p2 = np[2];
        }
        const float x0 = v0.x, x1 = v0.y, x2 = v1.x,
                    x3 = v1.y, x4 = v2.x, x5 = v2.y;

        // A = relu(x)+eps (bit==1 in table), Bv = relu(1-x)+eps (bit==0)
        const float A0 = fmaxf(x0, 0.0f) + EPS, B0 = fmaxf(1.0f - x0, 0.0f) + EPS;
        const float A1 = fmaxf(x1, 0.0f) + EPS, B1 = fmaxf(1.0f - x1, 0.0f) + EPS;
        const float A2 = fmaxf(x2, 0.0f) + EPS, B2 = fmaxf(1.0f - x2, 0.0f) + EPS;
        const float A3 = fmaxf(x3, 0.0f) + EPS, B3 = fmaxf(1.0f - x3, 0.0f) + EPS;
        const float A4 = fmaxf(x4, 0.0f) + EPS, B4 = fmaxf(1.0f - x4, 0.0f) + EPS;
        const float A5 = fmaxf(x5, 0.0f) + EPS, B5 = fmaxf(1.0f - x5, 0.0f) + EPS;

        // table idx i = b0*32+b1*16+b2*8 + b3*4+b4*2+b5 (MSB-first)
        float t01[4];
        t01[0] = A0 * A1;  t01[1] = A0 * B1;
        t01[2] = B0 * A1;  t01[3] = B0 * B1;
        float t34[4];
        t34[0] = A3 * A4;  t34[1] = A3 * B4;
        t34[2] = B3 * A4;  t34[3] = B3 * B4;

        float tlo[8];
        #pragma unroll
        for (int h = 0; h < 8; ++h)
            tlo[h] = t34[h >> 1] * ((h & 1) ? B5 : A5);

        float acc = 0.0f;
        #pragma unroll
        for (int h = 0; h < 8; ++h) {
            float s = 0.0f;
            #pragma unroll
            for (int l = 0; l < 8; ++l) s = fmaf(tlo[l], w[h * 8 + l], s);
            const float thi = t01[h >> 1] * ((h & 1) ? B2 : A2);  // on the fly
            acc = fmaf(thi, s, acc);
        }
        op[(size_t)it * 4 * N] = acc;
    }
}

extern "C" void kernel_launch(void* const* d_in, const int* in_sizes, int n_in,
                              void* d_out, int out_size, void* d_ws, size_t ws_size,
                              hipStream_t stream) {
    const float* inputs = (const float*)d_in[0];   // [B, N, 6] f32
    const float* lut    = (const float*)d_in[1];   // [N, 64]  f32
    float* out = (float*)d_out;                    // [B, N]   f32

    const int lut_sz = in_sizes[1];                // N*64
    const int N = lut_sz / 64;
    const int B = in_sizes[0] / (6 * N);

    dim3 grid(N / 64, B / 32);
    lut_kernel<<<grid, 256, 0, stream>>>(inputs, lut, out, N);
}